// Round 3
// baseline (661.085 us; speedup 1.0000x reference)
//
#include <hip/hip_runtime.h>
#include <stdint.h>
#include <stddef.h>

#define B_ 2
#define S_ 2048
#define D_ 1024
#define H_ 16
#define HD_ 64
#define FF_ 4096

typedef unsigned short u16;
typedef __attribute__((ext_vector_type(8))) short bf16x8;
typedef __attribute__((ext_vector_type(4))) float f32x4;

__device__ __forceinline__ u16 f2bf(float f) {
  unsigned u = __float_as_uint(f);
  u += 0x7fffu + ((u >> 16) & 1u);
  return (u16)(u >> 16);
}

__device__ __forceinline__ f32x4 mfma16(bf16x8 a, bf16x8 b, f32x4 c) {
  return __builtin_amdgcn_mfma_f32_16x16x32_bf16(a, b, c, 0, 0, 0);
}

__device__ __forceinline__ void gload16(const void* g, void* l) {
  __builtin_amdgcn_global_load_lds(
      (const __attribute__((address_space(1))) void*)g,
      (__attribute__((address_space(3))) void*)l, 16, 0, 0);
}

// ---------------- elementwise fp32 -> bf16 ----------------
__global__ __launch_bounds__(256) void cvt_kernel(const float* __restrict__ src,
                                                  u16* __restrict__ dst, int n) {
  int i = (blockIdx.x * 256 + threadIdx.x) * 4;
  if (i >= n) return;
  float4 v = *(const float4*)(src + i);
  ushort4 o = { f2bf(v.x), f2bf(v.y), f2bf(v.z), f2bf(v.w) };
  *(ushort4*)(dst + i) = o;
}

// ---------------- transpose + convert: W (K x N) fp32 -> WT (N x K) bf16 ----
__global__ __launch_bounds__(256) void transpose_cvt_kernel(
    const float* __restrict__ W, u16* __restrict__ WT, int K, int N) {
  __shared__ u16 t[32][33];
  int k0 = blockIdx.x * 32;
  int n0 = blockIdx.y * 32;
  int tid = threadIdx.x;
  int r = tid >> 3;         // 0..31
  int c = (tid & 7) << 2;   // 0..28
  float4 v = *(const float4*)(W + (size_t)(k0 + r) * N + n0 + c);
  t[r][c + 0] = f2bf(v.x); t[r][c + 1] = f2bf(v.y);
  t[r][c + 2] = f2bf(v.z); t[r][c + 3] = f2bf(v.w);
  __syncthreads();
  ushort4 o;
  o.x = t[c + 0][r]; o.y = t[c + 1][r]; o.z = t[c + 2][r]; o.w = t[c + 3][r];
  *(ushort4*)(WT + (size_t)(n0 + r) * K + k0 + c) = o;
}

// ---------------- GEMM: A (M x K) bf16 row-major, BT (N x K) bf16 ----------
// MODE 3: out bf16 row-major M x N, relu(+bias)         [ffn1]
template <int MODE>
__global__ __launch_bounds__(256) void gemm_bt(
    const u16* __restrict__ A, const u16* __restrict__ BT,
    const float* __restrict__ bias, void* __restrict__ outp,
    int M, int N, int K) {
  __shared__ __align__(16) u16 As[128 * 32];
  __shared__ __align__(16) u16 Bs[128 * 32];
  int tid = threadIdx.x;
  int lane = tid & 63;
  int wave = tid >> 6;
  int quad = lane >> 4;
  int l16 = lane & 15;
  int m0 = blockIdx.x * 128;
  int n0 = blockIdx.y * 128;
  int wm = (wave >> 1) * 64;
  int wn = (wave & 1) * 64;

  f32x4 zero = {0.f, 0.f, 0.f, 0.f};
  f32x4 acc[4][4];
#pragma unroll
  for (int i = 0; i < 4; i++)
#pragma unroll
    for (int j = 0; j < 4; j++) acc[i][j] = zero;

  int c0 = tid, c1 = tid + 256;
  const u16* ga0 = A + (size_t)(m0 + (c0 >> 2)) * K + (c0 & 3) * 8;
  const u16* ga1 = A + (size_t)(m0 + (c1 >> 2)) * K + (c1 & 3) * 8;
  const u16* gb0 = BT + (size_t)(n0 + (c0 >> 2)) * K + (c0 & 3) * 8;
  const u16* gb1 = BT + (size_t)(n0 + (c1 >> 2)) * K + (c1 & 3) * 8;

  for (int k0 = 0; k0 < K; k0 += 32) {
    gload16(ga0 + k0, &As[c0 * 8]);
    gload16(ga1 + k0, &As[c1 * 8]);
    gload16(gb0 + k0, &Bs[c0 * 8]);
    gload16(gb1 + k0, &Bs[c1 * 8]);
    __syncthreads();
    bf16x8 af[4], bfr[4];
#pragma unroll
    for (int i = 0; i < 4; i++)
      af[i] = *(const bf16x8*)&As[(wm + i * 16 + l16) * 32 + quad * 8];
#pragma unroll
    for (int j = 0; j < 4; j++)
      bfr[j] = *(const bf16x8*)&Bs[(wn + j * 16 + l16) * 32 + quad * 8];
#pragma unroll
    for (int i = 0; i < 4; i++)
#pragma unroll
      for (int j = 0; j < 4; j++)
        acc[i][j] = mfma16(af[i], bfr[j], acc[i][j]);
    __syncthreads();
  }

#pragma unroll
  for (int j = 0; j < 4; j++) {
    int gcol = n0 + wn + j * 16 + l16;
    float bv = bias[gcol];
#pragma unroll
    for (int i = 0; i < 4; i++) {
#pragma unroll
      for (int r = 0; r < 4; r++) {
        int grow = m0 + wm + i * 16 + quad * 4 + r;
        float val = acc[i][j][r] + bv;
        ((u16*)outp)[(size_t)grow * N + gcol] = f2bf(val > 0.f ? val : 0.f);
      }
    }
  }
}

// ---------------- split-K GEMM, fp32 atomic output ----------------
// grid.z = K-chunks; out must be zeroed first; bias added by chunk 0.
__global__ __launch_bounds__(256) void gemm_bt_sk(
    const u16* __restrict__ A, const u16* __restrict__ BT,
    const float* __restrict__ bias, float* __restrict__ outp,
    int M, int N, int K, int Kc) {
  __shared__ __align__(16) u16 As[128 * 32];
  __shared__ __align__(16) u16 Bs[128 * 32];
  int tid = threadIdx.x;
  int lane = tid & 63;
  int wave = tid >> 6;
  int quad = lane >> 4;
  int l16 = lane & 15;
  int m0 = blockIdx.x * 128;
  int n0 = blockIdx.y * 128;
  int kb = blockIdx.z * Kc;
  int wm = (wave >> 1) * 64;
  int wn = (wave & 1) * 64;

  f32x4 zero = {0.f, 0.f, 0.f, 0.f};
  f32x4 acc[4][4];
#pragma unroll
  for (int i = 0; i < 4; i++)
#pragma unroll
    for (int j = 0; j < 4; j++) acc[i][j] = zero;

  int c0 = tid, c1 = tid + 256;
  const u16* ga0 = A + (size_t)(m0 + (c0 >> 2)) * K + (c0 & 3) * 8 + kb;
  const u16* ga1 = A + (size_t)(m0 + (c1 >> 2)) * K + (c1 & 3) * 8 + kb;
  const u16* gb0 = BT + (size_t)(n0 + (c0 >> 2)) * K + (c0 & 3) * 8 + kb;
  const u16* gb1 = BT + (size_t)(n0 + (c1 >> 2)) * K + (c1 & 3) * 8 + kb;

  for (int k0 = 0; k0 < Kc; k0 += 32) {
    gload16(ga0 + k0, &As[c0 * 8]);
    gload16(ga1 + k0, &As[c1 * 8]);
    gload16(gb0 + k0, &Bs[c0 * 8]);
    gload16(gb1 + k0, &Bs[c1 * 8]);
    __syncthreads();
    bf16x8 af[4], bfr[4];
#pragma unroll
    for (int i = 0; i < 4; i++)
      af[i] = *(const bf16x8*)&As[(wm + i * 16 + l16) * 32 + quad * 8];
#pragma unroll
    for (int j = 0; j < 4; j++)
      bfr[j] = *(const bf16x8*)&Bs[(wn + j * 16 + l16) * 32 + quad * 8];
#pragma unroll
    for (int i = 0; i < 4; i++)
#pragma unroll
      for (int j = 0; j < 4; j++)
        acc[i][j] = mfma16(af[i], bfr[j], acc[i][j]);
    __syncthreads();
  }

  float biasmul = (blockIdx.z == 0) ? 1.f : 0.f;
#pragma unroll
  for (int j = 0; j < 4; j++) {
    int gcol = n0 + wn + j * 16 + l16;
    float bv = bias[gcol] * biasmul;
#pragma unroll
    for (int i = 0; i < 4; i++) {
#pragma unroll
      for (int r = 0; r < 4; r++) {
        int grow = m0 + wm + i * 16 + quad * 4 + r;
        atomicAdd(&outp[(size_t)grow * N + gcol], acc[i][j][r] + bv);
      }
    }
  }
}

// ---------------- fused QKV GEMM ----------------
__global__ __launch_bounds__(256) void gemm_qkv(
    const u16* __restrict__ A, const u16* __restrict__ BT,
    const float* __restrict__ bq, const float* __restrict__ bk,
    const float* __restrict__ bvp,
    u16* __restrict__ qb, u16* __restrict__ kb, u16* __restrict__ vb) {
  const int K = 1024;
  __shared__ __align__(16) u16 As[128 * 32];
  __shared__ __align__(16) u16 Bs[128 * 32];
  int tid = threadIdx.x;
  int lane = tid & 63;
  int wave = tid >> 6;
  int quad = lane >> 4;
  int l16 = lane & 15;
  int m0 = blockIdx.x * 128;
  int n0 = blockIdx.y * 128;
  int wm = (wave >> 1) * 64;
  int wn = (wave & 1) * 64;

  f32x4 zero = {0.f, 0.f, 0.f, 0.f};
  f32x4 acc[4][4];
#pragma unroll
  for (int i = 0; i < 4; i++)
#pragma unroll
    for (int j = 0; j < 4; j++) acc[i][j] = zero;

  int c0 = tid, c1 = tid + 256;
  const u16* ga0 = A + (size_t)(m0 + (c0 >> 2)) * K + (c0 & 3) * 8;
  const u16* ga1 = A + (size_t)(m0 + (c1 >> 2)) * K + (c1 & 3) * 8;
  const u16* gb0 = BT + (size_t)(n0 + (c0 >> 2)) * K + (c0 & 3) * 8;
  const u16* gb1 = BT + (size_t)(n0 + (c1 >> 2)) * K + (c1 & 3) * 8;

  for (int k0 = 0; k0 < K; k0 += 32) {
    gload16(ga0 + k0, &As[c0 * 8]);
    gload16(ga1 + k0, &As[c1 * 8]);
    gload16(gb0 + k0, &Bs[c0 * 8]);
    gload16(gb1 + k0, &Bs[c1 * 8]);
    __syncthreads();
    bf16x8 af[4], bfr[4];
#pragma unroll
    for (int i = 0; i < 4; i++)
      af[i] = *(const bf16x8*)&As[(wm + i * 16 + l16) * 32 + quad * 8];
#pragma unroll
    for (int j = 0; j < 4; j++)
      bfr[j] = *(const bf16x8*)&Bs[(wn + j * 16 + l16) * 32 + quad * 8];
#pragma unroll
    for (int i = 0; i < 4; i++)
#pragma unroll
      for (int j = 0; j < 4; j++)
        acc[i][j] = mfma16(af[i], bfr[j], acc[i][j]);
    __syncthreads();
  }

  int region = n0 >> 10;                       // uniform per block
  const float* bias = region == 0 ? bq : (region == 1 ? bk : bvp);
  u16* outp = region == 0 ? qb : (region == 1 ? kb : vb);

#pragma unroll
  for (int j = 0; j < 4; j++) {
    int gcol = (n0 & 1023) + wn + j * 16 + l16;  // col within region (0..1023)
    float bv = bias[gcol];
    int h = gcol >> 6, hd = gcol & 63;
#pragma unroll
    for (int i = 0; i < 4; i++) {
#pragma unroll
      for (int r = 0; r < 4; r++) {
        int grow = m0 + wm + i * 16 + quad * 4 + r;
        float val = acc[i][j][r] + bv;
        int b = grow >> 11, s = grow & 2047;
        if (region < 2) {
          outp[(((size_t)(b * H_ + h)) * S_ + s) * HD_ + hd] = f2bf(val);
        } else {
          outp[(((size_t)(b * H_ + h)) * HD_ + hd) * S_ + s] = f2bf(val);
        }
      }
    }
  }
}

// ---------------- flash attention, fixed-max + register prefetch -----------
// Per 32-key tile: K/V/mask frags for tile t+1 are loaded at the top of
// iteration t (wraparound addresses, branchless) so global-load latency is
// hidden behind the QK->exp->LDS->PV chain. No asm scheduling barrier: the
// compiler orders same-array LDS ops and inserts lgkmcnt itself.
__global__ __launch_bounds__(256, 4) void attn_kernel(
    const u16* __restrict__ q, const u16* __restrict__ k,
    const u16* __restrict__ vt, const int* __restrict__ mask,
    u16* __restrict__ ao) {
  __shared__ __align__(16) u16 pshm[4][16 * 40];
  int tid = threadIdx.x;
  int lane = tid & 63;
  int wave = tid >> 6;
  int quad = lane >> 4;
  int l16 = lane & 15;
  int bh = blockIdx.y;
  int b = bh >> 4;
  int h = bh & 15;
  int qrow0 = blockIdx.x * 64 + wave * 16;

  const u16* qh = q + (size_t)bh * S_ * HD_;
  const u16* kh = k + (size_t)bh * S_ * HD_;
  const u16* vh = vt + (size_t)bh * HD_ * S_;

  bf16x8 qf0 = *(const bf16x8*)(qh + (size_t)(qrow0 + l16) * HD_ + quad * 8);
  bf16x8 qf1 = *(const bf16x8*)(qh + (size_t)(qrow0 + l16) * HD_ + 32 + quad * 8);

  const u16* kbase = kh + (size_t)(2 * l16) * HD_ + quad * 8;  // even/odd keys
  const u16* vbase = vh + (size_t)l16 * S_ + quad * 8;
  const int* mbase = mask + b * S_ + 2 * l16;

  float l_part[4] = {0.f, 0.f, 0.f, 0.f};
  f32x4 zero = {0.f, 0.f, 0.f, 0.f};
  f32x4 o_acc[4];
#pragma unroll
  for (int c = 0; c < 4; c++) o_acc[c] = zero;

  u16* pw = &pshm[wave][0];
  const float cexp = 0.125f * 1.4426950408889634f;  // 1/sqrt(HD) * log2(e)

  // preload tile 0
  bf16x8 kc[4], vc[4];
  kc[0] = *(const bf16x8*)(kbase);
  kc[1] = *(const bf16x8*)(kbase + 32);
  kc[2] = *(const bf16x8*)(kbase + HD_);
  kc[3] = *(const bf16x8*)(kbase + HD_ + 32);
#pragma unroll
  for (int c = 0; c < 4; c++)
    vc[c] = *(const bf16x8*)(vbase + (size_t)(c * 16) * S_);
  int2 mk = *(const int2*)(mbase);

  for (int kt = 0; kt < S_; kt += 32) {
    int nkt = (kt + 32) & (S_ - 1);  // wraparound: harmless dummy on last iter
    bf16x8 kn[4], vn[4];
    const u16* knb = kbase + (size_t)nkt * HD_;
    kn[0] = *(const bf16x8*)(knb);
    kn[1] = *(const bf16x8*)(knb + 32);
    kn[2] = *(const bf16x8*)(knb + HD_);
    kn[3] = *(const bf16x8*)(knb + HD_ + 32);
#pragma unroll
    for (int c = 0; c < 4; c++)
      vn[c] = *(const bf16x8*)(vbase + (size_t)(c * 16) * S_ + nkt);
    int2 mkn = *(const int2*)(mbase + nkt);

    f32x4 s0 = zero, s1 = zero;
    s0 = mfma16(qf0, kc[0], s0);
    s0 = mfma16(qf1, kc[1], s0);
    s1 = mfma16(qf0, kc[2], s1);
    s1 = mfma16(qf1, kc[3], s1);

#pragma unroll
    for (int r = 0; r < 4; r++) {
      float e0 = exp2f(s0[r] * cexp);
      float e1 = exp2f(s1[r] * cexp);
      float p0 = mk.x ? e0 : 0.f;
      float p1 = mk.y ? e1 : 0.f;
      l_part[r] += p0 + p1;
      unsigned pk = (unsigned)f2bf(p0) | ((unsigned)f2bf(p1) << 16);
      *(unsigned*)&pw[(quad * 4 + r) * 40 + 2 * l16] = pk;
    }
    bf16x8 pf = *(const bf16x8*)&pw[l16 * 40 + quad * 8];
#pragma unroll
    for (int c = 0; c < 4; c++) o_acc[c] = mfma16(pf, vc[c], o_acc[c]);

#pragma unroll
    for (int c = 0; c < 4; c++) { kc[c] = kn[c]; vc[c] = vn[c]; }
    mk = mkn;
  }

#pragma unroll
  for (int r = 0; r < 4; r++) {
    float s = l_part[r];
#pragma unroll
    for (int off = 1; off < 16; off <<= 1) s += __shfl_xor(s, off);
    float inv = 1.f / s;
    int srow = qrow0 + quad * 4 + r;
#pragma unroll
    for (int c = 0; c < 4; c++) {
      float val = o_acc[c][r] * inv;
      ao[((size_t)(b * S_ + srow)) * D_ + h * HD_ + c * 16 + l16] = f2bf(val);
    }
  }
}

// ---------------- residual + layernorm ----------------
__global__ __launch_bounds__(256) void ln_kernel(
    const float* __restrict__ xa, const float* __restrict__ xadd,
    const float* __restrict__ g, const float* __restrict__ be,
    float* __restrict__ outf, u16* __restrict__ outb) {
  int row = blockIdx.x;
  int tid = threadIdx.x;
  int lane = tid & 63;
  int wv = tid >> 6;
  const float4 a = *(const float4*)(xa + (size_t)row * D_ + tid * 4);
  const float4 c = *(const float4*)(xadd + (size_t)row * D_ + tid * 4);
  float v0 = a.x + c.x, v1 = a.y + c.y, v2 = a.z + c.z, v3 = a.w + c.w;
  float s = v0 + v1 + v2 + v3;
  float sq = v0 * v0 + v1 * v1 + v2 * v2 + v3 * v3;
#pragma unroll
  for (int off = 1; off < 64; off <<= 1) {
    s += __shfl_xor(s, off);
    sq += __shfl_xor(sq, off);
  }
  __shared__ float red[8];
  if (lane == 0) { red[wv] = s; red[4 + wv] = sq; }
  __syncthreads();
  s = red[0] + red[1] + red[2] + red[3];
  sq = red[4] + red[5] + red[6] + red[7];
  float mean = s * (1.f / D_);
  float var = sq * (1.f / D_) - mean * mean;
  float rstd = rsqrtf(var + 1e-5f);
  const float4 gv = *(const float4*)(g + tid * 4);
  const float4 bv = *(const float4*)(be + tid * 4);
  float y0 = (v0 - mean) * rstd * gv.x + bv.x;
  float y1 = (v1 - mean) * rstd * gv.y + bv.y;
  float y2 = (v2 - mean) * rstd * gv.z + bv.z;
  float y3 = (v3 - mean) * rstd * gv.w + bv.w;
  float4 o = {y0, y1, y2, y3};
  *(float4*)(outf + (size_t)row * D_ + tid * 4) = o;
  if (outb) {
    ushort4 ob = {f2bf(y0), f2bf(y1), f2bf(y2), f2bf(y3)};
    *(ushort4*)(outb + (size_t)row * D_ + tid * 4) = ob;
  }
}

extern "C" void kernel_launch(void* const* d_in, const int* in_sizes, int n_in,
                              void* d_out, int out_size, void* d_ws, size_t ws_size,
                              hipStream_t stream) {
  const float* x = (const float*)d_in[0];
  const int* mask = (const int*)d_in[1];
  const float* Wq = (const float*)d_in[2];
  const float* bq = (const float*)d_in[3];
  const float* Wk = (const float*)d_in[4];
  const float* bk = (const float*)d_in[5];
  const float* Wv = (const float*)d_in[6];
  const float* bv = (const float*)d_in[7];
  const float* Wo = (const float*)d_in[8];
  const float* bo = (const float*)d_in[9];
  const float* W1 = (const float*)d_in[10];
  const float* b1 = (const float*)d_in[11];
  const float* W2 = (const float*)d_in[12];
  const float* b2 = (const float*)d_in[13];
  const float* g1 = (const float*)d_in[14];
  const float* be1 = (const float*)d_in[15];
  const float* g2 = (const float*)d_in[16];
  const float* be2 = (const float*)d_in[17];

  const size_t MB = 1ull << 20;
  char* ws = (char*)d_ws;
  u16* wTq = (u16*)(ws + 0 * MB);   // [wTq; wTk; wTv] contiguous = fused QKV BT
  u16* wTk = (u16*)(ws + 2 * MB);
  u16* wTv = (u16*)(ws + 4 * MB);
  u16* wTo = (u16*)(ws + 6 * MB);
  u16* w1T = (u16*)(ws + 8 * MB);   // FF x D
  u16* w2T = (u16*)(ws + 16 * MB);  // D x FF
  u16* xb  = (u16*)(ws + 24 * MB);
  u16* qb  = (u16*)(ws + 32 * MB);
  u16* kb  = (u16*)(ws + 40 * MB);
  u16* vb  = (u16*)(ws + 48 * MB);
  u16* ao  = (u16*)(ws + 56 * MB);
  float* proj = (float*)(ws + 64 * MB);
  float* x1f  = (float*)(ws + 24 * MB);  // reuse xb+qb (dead)
  u16*   x1b  = (u16*)(ws + 40 * MB);    // reuse kb (dead)
  u16*   h1   = (u16*)(ws + 48 * MB);    // reuse vb+ao (dead), 32 MB
  float* ffn2 = (float*)(ws + 80 * MB);

  // zero split-K accumulators (ws is re-poisoned to 0xAA before every call)
  hipMemsetAsync(proj, 0, (size_t)4096 * 1024 * 4, stream);
  hipMemsetAsync(ffn2, 0, (size_t)4096 * 1024 * 4, stream);

  // convert x to bf16
  cvt_kernel<<<dim3((B_ * S_ * D_) / 1024), dim3(256), 0, stream>>>(x, xb, B_ * S_ * D_);
  // transpose-convert weights
  transpose_cvt_kernel<<<dim3(32, 32), dim3(256), 0, stream>>>(Wq, wTq, D_, D_);
  transpose_cvt_kernel<<<dim3(32, 32), dim3(256), 0, stream>>>(Wk, wTk, D_, D_);
  transpose_cvt_kernel<<<dim3(32, 32), dim3(256), 0, stream>>>(Wv, wTv, D_, D_);
  transpose_cvt_kernel<<<dim3(32, 32), dim3(256), 0, stream>>>(Wo, wTo, D_, D_);
  transpose_cvt_kernel<<<dim3(32, 128), dim3(256), 0, stream>>>(W1, w1T, D_, FF_);
  transpose_cvt_kernel<<<dim3(128, 32), dim3(256), 0, stream>>>(W2, w2T, FF_, D_);

  // fused QKV projection (BT = [wTq;wTk;wTv] contiguous, N=3072)
  gemm_qkv<<<dim3(32, 24), dim3(256), 0, stream>>>(xb, wTq, bq, bk, bv, qb, kb, vb);

  // attention
  attn_kernel<<<dim3(S_ / 64, B_ * H_), dim3(256), 0, stream>>>(qb, kb, vb, mask, ao);

  // output projection, split-K x4 (N=1024 alone gives only 1 block/CU)
  gemm_bt_sk<<<dim3(32, 8, 4), dim3(256), 0, stream>>>(ao, wTo, bo, proj, 4096, 1024, 1024, 256);

  // LN1: x1 = LN(x + proj)
  ln_kernel<<<dim3(4096), dim3(256), 0, stream>>>(x, proj, g1, be1, x1f, x1b);

  // FFN
  gemm_bt<3><<<dim3(32, 32), dim3(256), 0, stream>>>(x1b, w1T, b1, h1, 4096, 4096, 1024);
  gemm_bt_sk<<<dim3(32, 8, 4), dim3(256), 0, stream>>>(h1, w2T, b2, ffn2, 4096, 1024, 4096, 1024);

  // LN2 -> out
  ln_kernel<<<dim3(4096), dim3(256), 0, stream>>>(x1f, ffn2, g2, be2, (float*)d_out, (u16*)nullptr);
}

// Round 4
// 431.822 us; speedup vs baseline: 1.5309x; 1.5309x over previous
//
#include <hip/hip_runtime.h>
#include <stdint.h>
#include <stddef.h>

#define B_ 2
#define S_ 2048
#define D_ 1024
#define H_ 16
#define HD_ 64
#define FF_ 4096

typedef unsigned short u16;
typedef __attribute__((ext_vector_type(8))) short bf16x8;
typedef __attribute__((ext_vector_type(4))) float f32x4;

__device__ __forceinline__ u16 f2bf(float f) {
  unsigned u = __float_as_uint(f);
  u += 0x7fffu + ((u >> 16) & 1u);
  return (u16)(u >> 16);
}

__device__ __forceinline__ f32x4 mfma16(bf16x8 a, bf16x8 b, f32x4 c) {
  return __builtin_amdgcn_mfma_f32_16x16x32_bf16(a, b, c, 0, 0, 0);
}

__device__ __forceinline__ void gload16(const void* g, void* l) {
  __builtin_amdgcn_global_load_lds(
      (const __attribute__((address_space(1))) void*)g,
      (__attribute__((address_space(3))) void*)l, 16, 0, 0);
}

// ---------------- elementwise fp32 -> bf16 ----------------
__global__ __launch_bounds__(256) void cvt_kernel(const float* __restrict__ src,
                                                  u16* __restrict__ dst, int n) {
  int i = (blockIdx.x * 256 + threadIdx.x) * 4;
  if (i >= n) return;
  float4 v = *(const float4*)(src + i);
  ushort4 o = { f2bf(v.x), f2bf(v.y), f2bf(v.z), f2bf(v.w) };
  *(ushort4*)(dst + i) = o;
}

// ---------------- transpose + convert: W (K x N) fp32 -> WT (N x K) bf16 ----
__global__ __launch_bounds__(256) void transpose_cvt_kernel(
    const float* __restrict__ W, u16* __restrict__ WT, int K, int N) {
  __shared__ u16 t[32][33];
  int k0 = blockIdx.x * 32;
  int n0 = blockIdx.y * 32;
  int tid = threadIdx.x;
  int r = tid >> 3;         // 0..31
  int c = (tid & 7) << 2;   // 0..28
  float4 v = *(const float4*)(W + (size_t)(k0 + r) * N + n0 + c);
  t[r][c + 0] = f2bf(v.x); t[r][c + 1] = f2bf(v.y);
  t[r][c + 2] = f2bf(v.z); t[r][c + 3] = f2bf(v.w);
  __syncthreads();
  ushort4 o;
  o.x = t[c + 0][r]; o.y = t[c + 1][r]; o.z = t[c + 2][r]; o.w = t[c + 3][r];
  *(ushort4*)(WT + (size_t)(n0 + r) * K + k0 + c) = o;
}

// ---------------- GEMM 128x128: A (M x K) bf16, BT (N x K) bf16 ------------
// MODE 3: out bf16 row-major M x N, relu(+bias)         [ffn1]
template <int MODE>
__global__ __launch_bounds__(256) void gemm_bt(
    const u16* __restrict__ A, const u16* __restrict__ BT,
    const float* __restrict__ bias, void* __restrict__ outp,
    int M, int N, int K) {
  __shared__ __align__(16) u16 As[128 * 32];
  __shared__ __align__(16) u16 Bs[128 * 32];
  int tid = threadIdx.x;
  int lane = tid & 63;
  int wave = tid >> 6;
  int quad = lane >> 4;
  int l16 = lane & 15;
  int m0 = blockIdx.x * 128;
  int n0 = blockIdx.y * 128;
  int wm = (wave >> 1) * 64;
  int wn = (wave & 1) * 64;

  f32x4 zero = {0.f, 0.f, 0.f, 0.f};
  f32x4 acc[4][4];
#pragma unroll
  for (int i = 0; i < 4; i++)
#pragma unroll
    for (int j = 0; j < 4; j++) acc[i][j] = zero;

  int c0 = tid, c1 = tid + 256;
  const u16* ga0 = A + (size_t)(m0 + (c0 >> 2)) * K + (c0 & 3) * 8;
  const u16* ga1 = A + (size_t)(m0 + (c1 >> 2)) * K + (c1 & 3) * 8;
  const u16* gb0 = BT + (size_t)(n0 + (c0 >> 2)) * K + (c0 & 3) * 8;
  const u16* gb1 = BT + (size_t)(n0 + (c1 >> 2)) * K + (c1 & 3) * 8;

  for (int k0 = 0; k0 < K; k0 += 32) {
    gload16(ga0 + k0, &As[c0 * 8]);
    gload16(ga1 + k0, &As[c1 * 8]);
    gload16(gb0 + k0, &Bs[c0 * 8]);
    gload16(gb1 + k0, &Bs[c1 * 8]);
    __syncthreads();
    bf16x8 af[4], bfr[4];
#pragma unroll
    for (int i = 0; i < 4; i++)
      af[i] = *(const bf16x8*)&As[(wm + i * 16 + l16) * 32 + quad * 8];
#pragma unroll
    for (int j = 0; j < 4; j++)
      bfr[j] = *(const bf16x8*)&Bs[(wn + j * 16 + l16) * 32 + quad * 8];
#pragma unroll
    for (int i = 0; i < 4; i++)
#pragma unroll
      for (int j = 0; j < 4; j++)
        acc[i][j] = mfma16(af[i], bfr[j], acc[i][j]);
    __syncthreads();
  }

#pragma unroll
  for (int j = 0; j < 4; j++) {
    int gcol = n0 + wn + j * 16 + l16;
    float bv = bias[gcol];
#pragma unroll
    for (int i = 0; i < 4; i++) {
#pragma unroll
      for (int r = 0; r < 4; r++) {
        int grow = m0 + wm + i * 16 + quad * 4 + r;
        float val = acc[i][j][r] + bv;
        ((u16*)outp)[(size_t)grow * N + gcol] = f2bf(val > 0.f ? val : 0.f);
      }
    }
  }
}

// ---------------- GEMM 128x64 tile, fp32 out (+bias) -----------------------
// For N=1024 GEMMs: grid (M/128, N/64) = 512 blocks -> 2 blocks/CU.
__global__ __launch_bounds__(256) void gemm_bt64(
    const u16* __restrict__ A, const u16* __restrict__ BT,
    const float* __restrict__ bias, float* __restrict__ outp,
    int M, int N, int K) {
  __shared__ __align__(16) u16 As[128 * 32];
  __shared__ __align__(16) u16 Bs[64 * 32];
  int tid = threadIdx.x;
  int lane = tid & 63;
  int wave = tid >> 6;
  int quad = lane >> 4;
  int l16 = lane & 15;
  int m0 = blockIdx.x * 128;
  int n0 = blockIdx.y * 64;
  int wm = (wave >> 1) * 64;
  int wn = (wave & 1) * 32;

  f32x4 zero = {0.f, 0.f, 0.f, 0.f};
  f32x4 acc[4][2];
#pragma unroll
  for (int i = 0; i < 4; i++)
#pragma unroll
    for (int j = 0; j < 2; j++) acc[i][j] = zero;

  int c0 = tid, c1 = tid + 256;
  const u16* ga0 = A + (size_t)(m0 + (c0 >> 2)) * K + (c0 & 3) * 8;
  const u16* ga1 = A + (size_t)(m0 + (c1 >> 2)) * K + (c1 & 3) * 8;
  const u16* gb0 = BT + (size_t)(n0 + (tid >> 2)) * K + (tid & 3) * 8;

  for (int k0 = 0; k0 < K; k0 += 32) {
    gload16(ga0 + k0, &As[c0 * 8]);
    gload16(ga1 + k0, &As[c1 * 8]);
    gload16(gb0 + k0, &Bs[tid * 8]);
    __syncthreads();
    bf16x8 af[4], bfr[2];
#pragma unroll
    for (int i = 0; i < 4; i++)
      af[i] = *(const bf16x8*)&As[(wm + i * 16 + l16) * 32 + quad * 8];
#pragma unroll
    for (int j = 0; j < 2; j++)
      bfr[j] = *(const bf16x8*)&Bs[(wn + j * 16 + l16) * 32 + quad * 8];
#pragma unroll
    for (int i = 0; i < 4; i++)
#pragma unroll
      for (int j = 0; j < 2; j++)
        acc[i][j] = mfma16(af[i], bfr[j], acc[i][j]);
    __syncthreads();
  }

#pragma unroll
  for (int j = 0; j < 2; j++) {
    int gcol = n0 + wn + j * 16 + l16;
    float bv = bias[gcol];
#pragma unroll
    for (int i = 0; i < 4; i++) {
#pragma unroll
      for (int r = 0; r < 4; r++) {
        int grow = m0 + wm + i * 16 + quad * 4 + r;
        outp[(size_t)grow * N + gcol] = acc[i][j][r] + bv;
      }
    }
  }
}

// ---------------- fused QKV GEMM ----------------
__global__ __launch_bounds__(256) void gemm_qkv(
    const u16* __restrict__ A, const u16* __restrict__ BT,
    const float* __restrict__ bq, const float* __restrict__ bk,
    const float* __restrict__ bvp,
    u16* __restrict__ qb, u16* __restrict__ kb, u16* __restrict__ vb) {
  const int K = 1024;
  __shared__ __align__(16) u16 As[128 * 32];
  __shared__ __align__(16) u16 Bs[128 * 32];
  int tid = threadIdx.x;
  int lane = tid & 63;
  int wave = tid >> 6;
  int quad = lane >> 4;
  int l16 = lane & 15;
  int m0 = blockIdx.x * 128;
  int n0 = blockIdx.y * 128;
  int wm = (wave >> 1) * 64;
  int wn = (wave & 1) * 64;

  f32x4 zero = {0.f, 0.f, 0.f, 0.f};
  f32x4 acc[4][4];
#pragma unroll
  for (int i = 0; i < 4; i++)
#pragma unroll
    for (int j = 0; j < 4; j++) acc[i][j] = zero;

  int c0 = tid, c1 = tid + 256;
  const u16* ga0 = A + (size_t)(m0 + (c0 >> 2)) * K + (c0 & 3) * 8;
  const u16* ga1 = A + (size_t)(m0 + (c1 >> 2)) * K + (c1 & 3) * 8;
  const u16* gb0 = BT + (size_t)(n0 + (c0 >> 2)) * K + (c0 & 3) * 8;
  const u16* gb1 = BT + (size_t)(n0 + (c1 >> 2)) * K + (c1 & 3) * 8;

  for (int k0 = 0; k0 < K; k0 += 32) {
    gload16(ga0 + k0, &As[c0 * 8]);
    gload16(ga1 + k0, &As[c1 * 8]);
    gload16(gb0 + k0, &Bs[c0 * 8]);
    gload16(gb1 + k0, &Bs[c1 * 8]);
    __syncthreads();
    bf16x8 af[4], bfr[4];
#pragma unroll
    for (int i = 0; i < 4; i++)
      af[i] = *(const bf16x8*)&As[(wm + i * 16 + l16) * 32 + quad * 8];
#pragma unroll
    for (int j = 0; j < 4; j++)
      bfr[j] = *(const bf16x8*)&Bs[(wn + j * 16 + l16) * 32 + quad * 8];
#pragma unroll
    for (int i = 0; i < 4; i++)
#pragma unroll
      for (int j = 0; j < 4; j++)
        acc[i][j] = mfma16(af[i], bfr[j], acc[i][j]);
    __syncthreads();
  }

  int region = n0 >> 10;                       // uniform per block
  const float* bias = region == 0 ? bq : (region == 1 ? bk : bvp);
  u16* outp = region == 0 ? qb : (region == 1 ? kb : vb);

#pragma unroll
  for (int j = 0; j < 4; j++) {
    int gcol = (n0 & 1023) + wn + j * 16 + l16;  // col within region (0..1023)
    float bv = bias[gcol];
    int h = gcol >> 6, hd = gcol & 63;
#pragma unroll
    for (int i = 0; i < 4; i++) {
#pragma unroll
      for (int r = 0; r < 4; r++) {
        int grow = m0 + wm + i * 16 + quad * 4 + r;
        float val = acc[i][j][r] + bv;
        int b = grow >> 11, s = grow & 2047;
        if (region < 2) {
          outp[(((size_t)(b * H_ + h)) * S_ + s) * HD_ + hd] = f2bf(val);
        } else {
          outp[(((size_t)(b * H_ + h)) * HD_ + hd) * S_ + s] = f2bf(val);
        }
      }
    }
  }
}

// ---------------- flash attention, LDS-staged K/V tiles --------------------
// TK=64 keys/tile. K-tile (key,dim) and V^T-tile (dim,key) staged via
// coalesced per-lane loads + ds_write_b128 into stride-72 (u16) padded rows
// (144 B = 9*16: b128-aligned, bank-balanced for all frag reads). Fixed-max
// streaming softmax (scores are small). P round-trips through a per-wave
// padded LDS tile (C-layout -> A-layout). 2-barrier m97-style K-loop.
__global__ __launch_bounds__(256, 4) void attn_kernel(
    const u16* __restrict__ q, const u16* __restrict__ k,
    const u16* __restrict__ vt, const int* __restrict__ mask,
    u16* __restrict__ ao) {
  __shared__ __align__(16) u16 Ks[64 * 72];
  __shared__ __align__(16) u16 Vs[64 * 72];
  __shared__ __align__(16) u16 Ps[4][16 * 72];
  int tid = threadIdx.x;
  int lane = tid & 63;
  int wave = tid >> 6;
  int quad = lane >> 4;
  int l16 = lane & 15;
  int bh = blockIdx.y;
  int b = bh >> 4;
  int h = bh & 15;
  int qrow0 = blockIdx.x * 64 + wave * 16;

  const u16* qh = q + (size_t)bh * S_ * HD_;
  const u16* kh = k + (size_t)bh * S_ * HD_;
  const u16* vh = vt + (size_t)bh * HD_ * S_;

  bf16x8 qf0 = *(const bf16x8*)(qh + (size_t)(qrow0 + l16) * HD_ + quad * 8);
  bf16x8 qf1 = *(const bf16x8*)(qh + (size_t)(qrow0 + l16) * HD_ + 32 + quad * 8);

  // staging: granule g (row g>>3, 8-elem col g&7); thread covers g=tid, tid+256
  int sr = tid >> 3, sc = tid & 7;
  const u16* kg0 = kh + sr * HD_ + sc * 8;
  const u16* kg1 = kh + (sr + 32) * HD_ + sc * 8;
  const u16* vg0 = vh + (size_t)sr * S_ + sc * 8;
  const u16* vg1 = vh + (size_t)(sr + 32) * S_ + sc * 8;
  int so0 = sr * 72 + sc * 8;
  int so1 = (sr + 32) * 72 + sc * 8;
  const int* mrow = mask + b * S_ + l16;

  float l_part[4] = {0.f, 0.f, 0.f, 0.f};
  f32x4 zero = {0.f, 0.f, 0.f, 0.f};
  f32x4 o_acc[4];
#pragma unroll
  for (int c = 0; c < 4; c++) o_acc[c] = zero;

  u16* pw = &Ps[wave][0];
  const float cexp = 0.125f * 1.4426950408889634f;  // 1/sqrt(HD) * log2(e)

  for (int kt = 0; kt < S_; kt += 64) {
    bf16x8 kv0 = *(const bf16x8*)(kg0 + (size_t)kt * HD_);
    bf16x8 kv1 = *(const bf16x8*)(kg1 + (size_t)kt * HD_);
    bf16x8 vv0 = *(const bf16x8*)(vg0 + kt);
    bf16x8 vv1 = *(const bf16x8*)(vg1 + kt);
    int mks[4];
#pragma unroll
    for (int kg = 0; kg < 4; kg++) mks[kg] = mrow[kt + kg * 16];

    __syncthreads();  // previous tile's compute done (WAR on Ks/Vs)
    *(bf16x8*)&Ks[so0] = kv0;
    *(bf16x8*)&Ks[so1] = kv1;
    *(bf16x8*)&Vs[so0] = vv0;
    *(bf16x8*)&Vs[so1] = vv1;
    __syncthreads();  // stage visible

    // QK^T: scores for 16 q-rows x 64 keys
    f32x4 s[4];
#pragma unroll
    for (int kg = 0; kg < 4; kg++) {
      bf16x8 kb0 = *(const bf16x8*)&Ks[(kg * 16 + l16) * 72 + quad * 8];
      bf16x8 kb1 = *(const bf16x8*)&Ks[(kg * 16 + l16) * 72 + 32 + quad * 8];
      f32x4 t0 = mfma16(qf0, kb0, zero);
      s[kg] = mfma16(qf1, kb1, t0);
    }
#pragma unroll
    for (int kg = 0; kg < 4; kg++) {
#pragma unroll
      for (int r = 0; r < 4; r++) {
        float e = exp2f(s[kg][r] * cexp);
        float p = mks[kg] ? e : 0.f;
        l_part[r] += p;
        pw[(quad * 4 + r) * 72 + kg * 16 + l16] = f2bf(p);
      }
    }
    // P (A-layout) x V^T
    bf16x8 pf0 = *(const bf16x8*)&pw[l16 * 72 + quad * 8];
    bf16x8 pf1 = *(const bf16x8*)&pw[l16 * 72 + 32 + quad * 8];
#pragma unroll
    for (int c = 0; c < 4; c++) {
      bf16x8 vf0 = *(const bf16x8*)&Vs[(c * 16 + l16) * 72 + quad * 8];
      bf16x8 vf1 = *(const bf16x8*)&Vs[(c * 16 + l16) * 72 + 32 + quad * 8];
      o_acc[c] = mfma16(pf0, vf0, o_acc[c]);
      o_acc[c] = mfma16(pf1, vf1, o_acc[c]);
    }
  }

#pragma unroll
  for (int r = 0; r < 4; r++) {
    float s = l_part[r];
#pragma unroll
    for (int off = 1; off < 16; off <<= 1) s += __shfl_xor(s, off);
    float inv = 1.f / s;
    int srow = qrow0 + quad * 4 + r;
#pragma unroll
    for (int c = 0; c < 4; c++) {
      float val = o_acc[c][r] * inv;
      ao[((size_t)(b * S_ + srow)) * D_ + h * HD_ + c * 16 + l16] = f2bf(val);
    }
  }
}

// ---------------- residual + layernorm ----------------
__global__ __launch_bounds__(256) void ln_kernel(
    const float* __restrict__ xa, const float* __restrict__ xadd,
    const float* __restrict__ g, const float* __restrict__ be,
    float* __restrict__ outf, u16* __restrict__ outb) {
  int row = blockIdx.x;
  int tid = threadIdx.x;
  int lane = tid & 63;
  int wv = tid >> 6;
  const float4 a = *(const float4*)(xa + (size_t)row * D_ + tid * 4);
  const float4 c = *(const float4*)(xadd + (size_t)row * D_ + tid * 4);
  float v0 = a.x + c.x, v1 = a.y + c.y, v2 = a.z + c.z, v3 = a.w + c.w;
  float s = v0 + v1 + v2 + v3;
  float sq = v0 * v0 + v1 * v1 + v2 * v2 + v3 * v3;
#pragma unroll
  for (int off = 1; off < 64; off <<= 1) {
    s += __shfl_xor(s, off);
    sq += __shfl_xor(sq, off);
  }
  __shared__ float red[8];
  if (lane == 0) { red[wv] = s; red[4 + wv] = sq; }
  __syncthreads();
  s = red[0] + red[1] + red[2] + red[3];
  sq = red[4] + red[5] + red[6] + red[7];
  float mean = s * (1.f / D_);
  float var = sq * (1.f / D_) - mean * mean;
  float rstd = rsqrtf(var + 1e-5f);
  const float4 gv = *(const float4*)(g + tid * 4);
  const float4 bv = *(const float4*)(be + tid * 4);
  float y0 = (v0 - mean) * rstd * gv.x + bv.x;
  float y1 = (v1 - mean) * rstd * gv.y + bv.y;
  float y2 = (v2 - mean) * rstd * gv.z + bv.z;
  float y3 = (v3 - mean) * rstd * gv.w + bv.w;
  float4 o = {y0, y1, y2, y3};
  *(float4*)(outf + (size_t)row * D_ + tid * 4) = o;
  if (outb) {
    ushort4 ob = {f2bf(y0), f2bf(y1), f2bf(y2), f2bf(y3)};
    *(ushort4*)(outb + (size_t)row * D_ + tid * 4) = ob;
  }
}

extern "C" void kernel_launch(void* const* d_in, const int* in_sizes, int n_in,
                              void* d_out, int out_size, void* d_ws, size_t ws_size,
                              hipStream_t stream) {
  const float* x = (const float*)d_in[0];
  const int* mask = (const int*)d_in[1];
  const float* Wq = (const float*)d_in[2];
  const float* bq = (const float*)d_in[3];
  const float* Wk = (const float*)d_in[4];
  const float* bk = (const float*)d_in[5];
  const float* Wv = (const float*)d_in[6];
  const float* bv = (const float*)d_in[7];
  const float* Wo = (const float*)d_in[8];
  const float* bo = (const float*)d_in[9];
  const float* W1 = (const float*)d_in[10];
  const float* b1 = (const float*)d_in[11];
  const float* W2 = (const float*)d_in[12];
  const float* b2 = (const float*)d_in[13];
  const float* g1 = (const float*)d_in[14];
  const float* be1 = (const float*)d_in[15];
  const float* g2 = (const float*)d_in[16];
  const float* be2 = (const float*)d_in[17];

  const size_t MB = 1ull << 20;
  char* ws = (char*)d_ws;
  u16* wTq = (u16*)(ws + 0 * MB);   // [wTq; wTk; wTv] contiguous = fused QKV BT
  u16* wTk = (u16*)(ws + 2 * MB);
  u16* wTv = (u16*)(ws + 4 * MB);
  u16* wTo = (u16*)(ws + 6 * MB);
  u16* w1T = (u16*)(ws + 8 * MB);   // FF x D
  u16* w2T = (u16*)(ws + 16 * MB);  // D x FF
  u16* xb  = (u16*)(ws + 24 * MB);
  u16* qb  = (u16*)(ws + 32 * MB);
  u16* kb  = (u16*)(ws + 40 * MB);
  u16* vb  = (u16*)(ws + 48 * MB);
  u16* ao  = (u16*)(ws + 56 * MB);
  float* proj = (float*)(ws + 64 * MB);
  float* x1f  = (float*)(ws + 24 * MB);  // reuse xb+qb (dead)
  u16*   x1b  = (u16*)(ws + 40 * MB);    // reuse kb (dead)
  u16*   h1   = (u16*)(ws + 48 * MB);    // reuse vb+ao+proj (dead after LN1)
  float* ffn2 = (float*)(ws + 80 * MB);

  // convert x to bf16
  cvt_kernel<<<dim3((B_ * S_ * D_) / 1024), dim3(256), 0, stream>>>(x, xb, B_ * S_ * D_);
  // transpose-convert weights
  transpose_cvt_kernel<<<dim3(32, 32), dim3(256), 0, stream>>>(Wq, wTq, D_, D_);
  transpose_cvt_kernel<<<dim3(32, 32), dim3(256), 0, stream>>>(Wk, wTk, D_, D_);
  transpose_cvt_kernel<<<dim3(32, 32), dim3(256), 0, stream>>>(Wv, wTv, D_, D_);
  transpose_cvt_kernel<<<dim3(32, 32), dim3(256), 0, stream>>>(Wo, wTo, D_, D_);
  transpose_cvt_kernel<<<dim3(32, 128), dim3(256), 0, stream>>>(W1, w1T, D_, FF_);
  transpose_cvt_kernel<<<dim3(128, 32), dim3(256), 0, stream>>>(W2, w2T, FF_, D_);

  // fused QKV projection (BT = [wTq;wTk;wTv] contiguous, N=3072)
  gemm_qkv<<<dim3(32, 24), dim3(256), 0, stream>>>(xb, wTq, bq, bk, bv, qb, kb, vb);

  // attention (LDS-staged)
  attn_kernel<<<dim3(S_ / 64, B_ * H_), dim3(256), 0, stream>>>(qb, kb, vb, mask, ao);

  // output projection (TN=64 tiles: 512 blocks, 2/CU)
  gemm_bt64<<<dim3(32, 16), dim3(256), 0, stream>>>(ao, wTo, bo, proj, 4096, 1024, 1024);

  // LN1: x1 = LN(x + proj)
  ln_kernel<<<dim3(4096), dim3(256), 0, stream>>>(x, proj, g1, be1, x1f, x1b);

  // FFN
  gemm_bt<3><<<dim3(32, 32), dim3(256), 0, stream>>>(x1b, w1T, b1, h1, 4096, 4096, 1024);
  gemm_bt64<<<dim3(32, 16), dim3(256), 0, stream>>>(h1, w2T, b2, ffn2, 4096, 1024, 4096);

  // LN2 -> out
  ln_kernel<<<dim3(4096), dim3(256), 0, stream>>>(x1f, ffn2, g2, be2, (float*)d_out, (u16*)nullptr);
}

// Round 5
// 406.878 us; speedup vs baseline: 1.6248x; 1.0613x over previous
//
#include <hip/hip_runtime.h>
#include <stdint.h>
#include <stddef.h>

#define B_ 2
#define S_ 2048
#define D_ 1024
#define H_ 16
#define HD_ 64
#define FF_ 4096

typedef unsigned short u16;
typedef __attribute__((ext_vector_type(8))) short bf16x8;
typedef __attribute__((ext_vector_type(4))) float f32x4;

__device__ __forceinline__ u16 f2bf(float f) {
  unsigned u = __float_as_uint(f);
  u += 0x7fffu + ((u >> 16) & 1u);
  return (u16)(u >> 16);
}

__device__ __forceinline__ f32x4 mfma16(bf16x8 a, bf16x8 b, f32x4 c) {
  return __builtin_amdgcn_mfma_f32_16x16x32_bf16(a, b, c, 0, 0, 0);
}

__device__ __forceinline__ void gload16(const void* g, void* l) {
  __builtin_amdgcn_global_load_lds(
      (const __attribute__((address_space(1))) void*)g,
      (__attribute__((address_space(3))) void*)l, 16, 0, 0);
}

// ---------------- elementwise fp32 -> bf16 ----------------
__global__ __launch_bounds__(256) void cvt_kernel(const float* __restrict__ src,
                                                  u16* __restrict__ dst, int n) {
  int i = (blockIdx.x * 256 + threadIdx.x) * 4;
  if (i >= n) return;
  float4 v = *(const float4*)(src + i);
  ushort4 o = { f2bf(v.x), f2bf(v.y), f2bf(v.z), f2bf(v.w) };
  *(ushort4*)(dst + i) = o;
}

// ---------------- transpose + convert: W (K x N) fp32 -> WT (N x K) bf16 ----
__global__ __launch_bounds__(256) void transpose_cvt_kernel(
    const float* __restrict__ W, u16* __restrict__ WT, int K, int N) {
  __shared__ u16 t[32][33];
  int k0 = blockIdx.x * 32;
  int n0 = blockIdx.y * 32;
  int tid = threadIdx.x;
  int r = tid >> 3;         // 0..31
  int c = (tid & 7) << 2;   // 0..28
  float4 v = *(const float4*)(W + (size_t)(k0 + r) * N + n0 + c);
  t[r][c + 0] = f2bf(v.x); t[r][c + 1] = f2bf(v.y);
  t[r][c + 2] = f2bf(v.z); t[r][c + 3] = f2bf(v.w);
  __syncthreads();
  ushort4 o;
  o.x = t[c + 0][r]; o.y = t[c + 1][r]; o.z = t[c + 2][r]; o.w = t[c + 3][r];
  *(ushort4*)(WT + (size_t)(n0 + r) * K + k0 + c) = o;
}

// ---------------- GEMM 128x128, out bf16 + relu (+bias)  [ffn1] ------------
__global__ __launch_bounds__(256) void gemm_bt_relu(
    const u16* __restrict__ A, const u16* __restrict__ BT,
    const float* __restrict__ bias, u16* __restrict__ outp,
    int M, int N, int K) {
  __shared__ __align__(16) u16 As[128 * 32];
  __shared__ __align__(16) u16 Bs[128 * 32];
  int tid = threadIdx.x;
  int lane = tid & 63;
  int wave = tid >> 6;
  int quad = lane >> 4;
  int l16 = lane & 15;
  int m0 = blockIdx.x * 128;
  int n0 = blockIdx.y * 128;
  int wm = (wave >> 1) * 64;
  int wn = (wave & 1) * 64;

  f32x4 zero = {0.f, 0.f, 0.f, 0.f};
  f32x4 acc[4][4];
#pragma unroll
  for (int i = 0; i < 4; i++)
#pragma unroll
    for (int j = 0; j < 4; j++) acc[i][j] = zero;

  int c0 = tid, c1 = tid + 256;
  const u16* ga0 = A + (size_t)(m0 + (c0 >> 2)) * K + (c0 & 3) * 8;
  const u16* ga1 = A + (size_t)(m0 + (c1 >> 2)) * K + (c1 & 3) * 8;
  const u16* gb0 = BT + (size_t)(n0 + (c0 >> 2)) * K + (c0 & 3) * 8;
  const u16* gb1 = BT + (size_t)(n0 + (c1 >> 2)) * K + (c1 & 3) * 8;

  for (int k0 = 0; k0 < K; k0 += 32) {
    gload16(ga0 + k0, &As[c0 * 8]);
    gload16(ga1 + k0, &As[c1 * 8]);
    gload16(gb0 + k0, &Bs[c0 * 8]);
    gload16(gb1 + k0, &Bs[c1 * 8]);
    __syncthreads();
    bf16x8 af[4], bfr[4];
#pragma unroll
    for (int i = 0; i < 4; i++)
      af[i] = *(const bf16x8*)&As[(wm + i * 16 + l16) * 32 + quad * 8];
#pragma unroll
    for (int j = 0; j < 4; j++)
      bfr[j] = *(const bf16x8*)&Bs[(wn + j * 16 + l16) * 32 + quad * 8];
#pragma unroll
    for (int i = 0; i < 4; i++)
#pragma unroll
      for (int j = 0; j < 4; j++)
        acc[i][j] = mfma16(af[i], bfr[j], acc[i][j]);
    __syncthreads();
  }

#pragma unroll
  for (int j = 0; j < 4; j++) {
    int gcol = n0 + wn + j * 16 + l16;
    float bv = bias[gcol];
#pragma unroll
    for (int i = 0; i < 4; i++) {
#pragma unroll
      for (int r = 0; r < 4; r++) {
        int grow = m0 + wm + i * 16 + quad * 4 + r;
        float val = acc[i][j][r] + bv;
        outp[(size_t)grow * N + gcol] = f2bf(val > 0.f ? val : 0.f);
      }
    }
  }
}

// ---------------- GEMM 128x128 split-K x2, separate fp32 outputs -----------
// grid.z: z covers K-range [z*Kc, (z+1)*Kc); writes outp + z*M*N.
// No atomics/memsets; partials summed inside the LN kernel. Bias at z=0.
__global__ __launch_bounds__(256) void gemm_bt_sk2(
    const u16* __restrict__ A, const u16* __restrict__ BT,
    const float* __restrict__ bias, float* __restrict__ outp,
    int M, int N, int K, int Kc) {
  __shared__ __align__(16) u16 As[128 * 32];
  __shared__ __align__(16) u16 Bs[128 * 32];
  int tid = threadIdx.x;
  int lane = tid & 63;
  int wave = tid >> 6;
  int quad = lane >> 4;
  int l16 = lane & 15;
  int m0 = blockIdx.x * 128;
  int n0 = blockIdx.y * 128;
  int kb = blockIdx.z * Kc;
  int wm = (wave >> 1) * 64;
  int wn = (wave & 1) * 64;

  f32x4 zero = {0.f, 0.f, 0.f, 0.f};
  f32x4 acc[4][4];
#pragma unroll
  for (int i = 0; i < 4; i++)
#pragma unroll
    for (int j = 0; j < 4; j++) acc[i][j] = zero;

  int c0 = tid, c1 = tid + 256;
  const u16* ga0 = A + (size_t)(m0 + (c0 >> 2)) * K + (c0 & 3) * 8 + kb;
  const u16* ga1 = A + (size_t)(m0 + (c1 >> 2)) * K + (c1 & 3) * 8 + kb;
  const u16* gb0 = BT + (size_t)(n0 + (c0 >> 2)) * K + (c0 & 3) * 8 + kb;
  const u16* gb1 = BT + (size_t)(n0 + (c1 >> 2)) * K + (c1 & 3) * 8 + kb;

  for (int k0 = 0; k0 < Kc; k0 += 32) {
    gload16(ga0 + k0, &As[c0 * 8]);
    gload16(ga1 + k0, &As[c1 * 8]);
    gload16(gb0 + k0, &Bs[c0 * 8]);
    gload16(gb1 + k0, &Bs[c1 * 8]);
    __syncthreads();
    bf16x8 af[4], bfr[4];
#pragma unroll
    for (int i = 0; i < 4; i++)
      af[i] = *(const bf16x8*)&As[(wm + i * 16 + l16) * 32 + quad * 8];
#pragma unroll
    for (int j = 0; j < 4; j++)
      bfr[j] = *(const bf16x8*)&Bs[(wn + j * 16 + l16) * 32 + quad * 8];
#pragma unroll
    for (int i = 0; i < 4; i++)
#pragma unroll
      for (int j = 0; j < 4; j++)
        acc[i][j] = mfma16(af[i], bfr[j], acc[i][j]);
    __syncthreads();
  }

  float* outz = outp + (size_t)blockIdx.z * M * N;
  float biasmul = (blockIdx.z == 0) ? 1.f : 0.f;
#pragma unroll
  for (int j = 0; j < 4; j++) {
    int gcol = n0 + wn + j * 16 + l16;
    float bv = bias[gcol] * biasmul;
#pragma unroll
    for (int i = 0; i < 4; i++) {
#pragma unroll
      for (int r = 0; r < 4; r++) {
        int grow = m0 + wm + i * 16 + quad * 4 + r;
        outz[(size_t)grow * N + gcol] = acc[i][j][r] + bv;
      }
    }
  }
}

// ---------------- fused QKV GEMM (q pre-scaled by 1/sqrt(HD)*log2e) --------
__global__ __launch_bounds__(256) void gemm_qkv(
    const u16* __restrict__ A, const u16* __restrict__ BT,
    const float* __restrict__ bq, const float* __restrict__ bk,
    const float* __restrict__ bvp,
    u16* __restrict__ qb, u16* __restrict__ kb, u16* __restrict__ vb) {
  const int K = 1024;
  __shared__ __align__(16) u16 As[128 * 32];
  __shared__ __align__(16) u16 Bs[128 * 32];
  int tid = threadIdx.x;
  int lane = tid & 63;
  int wave = tid >> 6;
  int quad = lane >> 4;
  int l16 = lane & 15;
  int m0 = blockIdx.x * 128;
  int n0 = blockIdx.y * 128;
  int wm = (wave >> 1) * 64;
  int wn = (wave & 1) * 64;

  f32x4 zero = {0.f, 0.f, 0.f, 0.f};
  f32x4 acc[4][4];
#pragma unroll
  for (int i = 0; i < 4; i++)
#pragma unroll
    for (int j = 0; j < 4; j++) acc[i][j] = zero;

  int c0 = tid, c1 = tid + 256;
  const u16* ga0 = A + (size_t)(m0 + (c0 >> 2)) * K + (c0 & 3) * 8;
  const u16* ga1 = A + (size_t)(m0 + (c1 >> 2)) * K + (c1 & 3) * 8;
  const u16* gb0 = BT + (size_t)(n0 + (c0 >> 2)) * K + (c0 & 3) * 8;
  const u16* gb1 = BT + (size_t)(n0 + (c1 >> 2)) * K + (c1 & 3) * 8;

  for (int k0 = 0; k0 < K; k0 += 32) {
    gload16(ga0 + k0, &As[c0 * 8]);
    gload16(ga1 + k0, &As[c1 * 8]);
    gload16(gb0 + k0, &Bs[c0 * 8]);
    gload16(gb1 + k0, &Bs[c1 * 8]);
    __syncthreads();
    bf16x8 af[4], bfr[4];
#pragma unroll
    for (int i = 0; i < 4; i++)
      af[i] = *(const bf16x8*)&As[(wm + i * 16 + l16) * 32 + quad * 8];
#pragma unroll
    for (int j = 0; j < 4; j++)
      bfr[j] = *(const bf16x8*)&Bs[(wn + j * 16 + l16) * 32 + quad * 8];
#pragma unroll
    for (int i = 0; i < 4; i++)
#pragma unroll
      for (int j = 0; j < 4; j++)
        acc[i][j] = mfma16(af[i], bfr[j], acc[i][j]);
    __syncthreads();
  }

  int region = n0 >> 10;                       // uniform per block
  const float* bias = region == 0 ? bq : (region == 1 ? bk : bvp);
  u16* outp = region == 0 ? qb : (region == 1 ? kb : vb);
  float scale = region == 0 ? 0.125f * 1.4426950408889634f : 1.f;

#pragma unroll
  for (int j = 0; j < 4; j++) {
    int gcol = (n0 & 1023) + wn + j * 16 + l16;  // col within region
    float bv = bias[gcol];
    int h = gcol >> 6, hd = gcol & 63;
#pragma unroll
    for (int i = 0; i < 4; i++) {
#pragma unroll
      for (int r = 0; r < 4; r++) {
        int grow = m0 + wm + i * 16 + quad * 4 + r;
        float val = (acc[i][j][r] + bv) * scale;
        int b = grow >> 11, s = grow & 2047;
        if (region < 2) {
          outp[(((size_t)(b * H_ + h)) * S_ + s) * HD_ + hd] = f2bf(val);
        } else {
          outp[(((size_t)(b * H_ + h)) * HD_ + hd) * S_ + s] = f2bf(val);
        }
      }
    }
  }
}

// ---------------- flash attention, LDS-staged, even/odd packed P -----------
// K staged row-PERMUTED (even keys -> rows 0..15, odd -> 16..31 per 32-group)
// so each lane's two score outputs are ADJACENT keys -> packed b32 P-writes
// (v_perm truncation pack), <=2-way banks (free). Q pre-scaled at projection.
__global__ __launch_bounds__(256, 4) void attn_kernel(
    const u16* __restrict__ q, const u16* __restrict__ k,
    const u16* __restrict__ vt, const int* __restrict__ mask,
    u16* __restrict__ ao) {
  __shared__ __align__(16) u16 Ks[64 * 72];
  __shared__ __align__(16) u16 Vs[64 * 72];
  __shared__ __align__(16) u16 Ps[4][16 * 72];
  int tid = threadIdx.x;
  int lane = tid & 63;
  int wave = tid >> 6;
  int quad = lane >> 4;
  int l16 = lane & 15;
  int bh = blockIdx.y;
  int b = bh >> 4;
  int h = bh & 15;
  int qrow0 = blockIdx.x * 64 + wave * 16;

  const u16* qh = q + (size_t)bh * S_ * HD_;
  const u16* kh = k + (size_t)bh * S_ * HD_;
  const u16* vh = vt + (size_t)bh * HD_ * S_;

  bf16x8 qf0 = *(const bf16x8*)(qh + (size_t)(qrow0 + l16) * HD_ + quad * 8);
  bf16x8 qf1 = *(const bf16x8*)(qh + (size_t)(qrow0 + l16) * HD_ + 32 + quad * 8);

  int sr = tid >> 3, sc = tid & 7;
  const u16* kg0 = kh + sr * HD_ + sc * 8;
  const u16* kg1 = kh + (sr + 32) * HD_ + sc * 8;
  const u16* vg0 = vh + (size_t)sr * S_ + sc * 8;
  const u16* vg1 = vh + (size_t)(sr + 32) * S_ + sc * 8;
  int kr0 = (sr & 1) * 16 + (sr >> 1);   // permuted row for key sr
  int ko0 = kr0 * 72 + sc * 8;
  int ko1 = (32 + kr0) * 72 + sc * 8;    // key sr+32 -> group 1
  int vo0 = sr * 72 + sc * 8;
  int vo1 = (sr + 32) * 72 + sc * 8;
  const int* mrow = mask + b * S_ + 2 * l16;

  float l_part[4] = {0.f, 0.f, 0.f, 0.f};
  f32x4 zero = {0.f, 0.f, 0.f, 0.f};
  f32x4 o_acc[4];
#pragma unroll
  for (int c = 0; c < 4; c++) o_acc[c] = zero;

  u16* pw = &Ps[wave][0];

  for (int kt = 0; kt < S_; kt += 64) {
    bf16x8 kv0 = *(const bf16x8*)(kg0 + (size_t)kt * HD_);
    bf16x8 kv1 = *(const bf16x8*)(kg1 + (size_t)kt * HD_);
    bf16x8 vv0 = *(const bf16x8*)(vg0 + kt);
    bf16x8 vv1 = *(const bf16x8*)(vg1 + kt);
    int2 mk0 = *(const int2*)(mrow + kt);
    int2 mk1 = *(const int2*)(mrow + kt + 32);

    __syncthreads();  // previous tile's compute done (WAR on Ks/Vs)
    *(bf16x8*)&Ks[ko0] = kv0;
    *(bf16x8*)&Ks[ko1] = kv1;
    *(bf16x8*)&Vs[vo0] = vv0;
    *(bf16x8*)&Vs[vo1] = vv1;
    __syncthreads();  // stage visible

#pragma unroll
    for (int g = 0; g < 2; g++) {
      int2 mk = g == 0 ? mk0 : mk1;
      f32x4 se, so;
      {
        int rowb = (g * 32 + l16) * 72;
        bf16x8 e0 = *(const bf16x8*)&Ks[rowb + quad * 8];
        bf16x8 e1 = *(const bf16x8*)&Ks[rowb + 32 + quad * 8];
        se = mfma16(qf1, e1, mfma16(qf0, e0, zero));
      }
      {
        int rowb = (g * 32 + 16 + l16) * 72;
        bf16x8 o0 = *(const bf16x8*)&Ks[rowb + quad * 8];
        bf16x8 o1 = *(const bf16x8*)&Ks[rowb + 32 + quad * 8];
        so = mfma16(qf1, o1, mfma16(qf0, o0, zero));
      }
#pragma unroll
      for (int r = 0; r < 4; r++) {
        float e0 = exp2f(se[r]);
        float e1 = exp2f(so[r]);
        float p0 = mk.x ? e0 : 0.f;
        float p1 = mk.y ? e1 : 0.f;
        l_part[r] += p0 + p1;
        unsigned pk = __builtin_amdgcn_perm(__float_as_uint(p1),
                                            __float_as_uint(p0), 0x07060302u);
        *(unsigned*)&pw[(quad * 4 + r) * 72 + g * 32 + 2 * l16] = pk;
      }
    }
    bf16x8 pf0 = *(const bf16x8*)&pw[l16 * 72 + quad * 8];
    bf16x8 pf1 = *(const bf16x8*)&pw[l16 * 72 + 32 + quad * 8];
#pragma unroll
    for (int c = 0; c < 4; c++) {
      bf16x8 vf0 = *(const bf16x8*)&Vs[(c * 16 + l16) * 72 + quad * 8];
      bf16x8 vf1 = *(const bf16x8*)&Vs[(c * 16 + l16) * 72 + 32 + quad * 8];
      o_acc[c] = mfma16(pf0, vf0, o_acc[c]);
      o_acc[c] = mfma16(pf1, vf1, o_acc[c]);
    }
  }

#pragma unroll
  for (int r = 0; r < 4; r++) {
    float s = l_part[r];
#pragma unroll
    for (int off = 1; off < 16; off <<= 1) s += __shfl_xor(s, off);
    float inv = 1.f / s;
    int srow = qrow0 + quad * 4 + r;
#pragma unroll
    for (int c = 0; c < 4; c++) {
      float val = o_acc[c][r] * inv;
      ao[((size_t)(b * S_ + srow)) * D_ + h * HD_ + c * 16 + l16] = f2bf(val);
    }
  }
}

// ---------------- residual (2 partials) + layernorm ----------------
__global__ __launch_bounds__(256) void ln_kernel(
    const float* __restrict__ xa, const float* __restrict__ add0,
    const float* __restrict__ add1,
    const float* __restrict__ g, const float* __restrict__ be,
    float* __restrict__ outf, u16* __restrict__ outb) {
  int row = blockIdx.x;
  int tid = threadIdx.x;
  int lane = tid & 63;
  int wv = tid >> 6;
  const float4 a = *(const float4*)(xa + (size_t)row * D_ + tid * 4);
  const float4 c = *(const float4*)(add0 + (size_t)row * D_ + tid * 4);
  const float4 d = *(const float4*)(add1 + (size_t)row * D_ + tid * 4);
  float v0 = a.x + c.x + d.x, v1 = a.y + c.y + d.y;
  float v2 = a.z + c.z + d.z, v3 = a.w + c.w + d.w;
  float s = v0 + v1 + v2 + v3;
  float sq = v0 * v0 + v1 * v1 + v2 * v2 + v3 * v3;
#pragma unroll
  for (int off = 1; off < 64; off <<= 1) {
    s += __shfl_xor(s, off);
    sq += __shfl_xor(sq, off);
  }
  __shared__ float red[8];
  if (lane == 0) { red[wv] = s; red[4 + wv] = sq; }
  __syncthreads();
  s = red[0] + red[1] + red[2] + red[3];
  sq = red[4] + red[5] + red[6] + red[7];
  float mean = s * (1.f / D_);
  float var = sq * (1.f / D_) - mean * mean;
  float rstd = rsqrtf(var + 1e-5f);
  const float4 gv = *(const float4*)(g + tid * 4);
  const float4 bv = *(const float4*)(be + tid * 4);
  float y0 = (v0 - mean) * rstd * gv.x + bv.x;
  float y1 = (v1 - mean) * rstd * gv.y + bv.y;
  float y2 = (v2 - mean) * rstd * gv.z + bv.z;
  float y3 = (v3 - mean) * rstd * gv.w + bv.w;
  float4 o = {y0, y1, y2, y3};
  *(float4*)(outf + (size_t)row * D_ + tid * 4) = o;
  if (outb) {
    ushort4 ob = {f2bf(y0), f2bf(y1), f2bf(y2), f2bf(y3)};
    *(ushort4*)(outb + (size_t)row * D_ + tid * 4) = ob;
  }
}

extern "C" void kernel_launch(void* const* d_in, const int* in_sizes, int n_in,
                              void* d_out, int out_size, void* d_ws, size_t ws_size,
                              hipStream_t stream) {
  const float* x = (const float*)d_in[0];
  const int* mask = (const int*)d_in[1];
  const float* Wq = (const float*)d_in[2];
  const float* bq = (const float*)d_in[3];
  const float* Wk = (const float*)d_in[4];
  const float* bk = (const float*)d_in[5];
  const float* Wv = (const float*)d_in[6];
  const float* bv = (const float*)d_in[7];
  const float* Wo = (const float*)d_in[8];
  const float* bo = (const float*)d_in[9];
  const float* W1 = (const float*)d_in[10];
  const float* b1 = (const float*)d_in[11];
  const float* W2 = (const float*)d_in[12];
  const float* b2 = (const float*)d_in[13];
  const float* g1 = (const float*)d_in[14];
  const float* be1 = (const float*)d_in[15];
  const float* g2 = (const float*)d_in[16];
  const float* be2 = (const float*)d_in[17];

  const size_t MB = 1ull << 20;
  char* ws = (char*)d_ws;
  u16* wTq = (u16*)(ws + 0 * MB);   // [wTq;wTk;wTv] contiguous = fused QKV BT
  u16* wTk = (u16*)(ws + 2 * MB);
  u16* wTv = (u16*)(ws + 4 * MB);
  u16* wTo = (u16*)(ws + 6 * MB);
  u16* w1T = (u16*)(ws + 8 * MB);   // FF x D
  u16* w2T = (u16*)(ws + 16 * MB);  // D x FF
  u16* xb  = (u16*)(ws + 24 * MB);
  u16* qb  = (u16*)(ws + 32 * MB);
  u16* kb  = (u16*)(ws + 40 * MB);
  u16* vb  = (u16*)(ws + 48 * MB);
  u16* ao  = (u16*)(ws + 56 * MB);
  float* proj = (float*)(ws + 64 * MB);  // 2 halves x 16 MB -> 64..96
  float* x1f  = (float*)(ws + 24 * MB);  // reuse xb+qb (dead after attn)
  u16*   x1b  = (u16*)(ws + 40 * MB);    // reuse kb (dead after attn)
  u16*   h1   = (u16*)(ws + 96 * MB);    // 32 MB: 96..128
  float* ffn2 = (float*)(ws + 48 * MB);  // 2 halves x 16 MB: vb+ao+... wait
  // regions at FFN2 time: dead = vb(48..56), ao(56..64), proj(64..96) after LN1
  // ffn2 = 48..80 (2x16 MB contiguous) -- all dead by then.

  cvt_kernel<<<dim3((B_ * S_ * D_) / 1024), dim3(256), 0, stream>>>(x, xb, B_ * S_ * D_);
  transpose_cvt_kernel<<<dim3(32, 32), dim3(256), 0, stream>>>(Wq, wTq, D_, D_);
  transpose_cvt_kernel<<<dim3(32, 32), dim3(256), 0, stream>>>(Wk, wTk, D_, D_);
  transpose_cvt_kernel<<<dim3(32, 32), dim3(256), 0, stream>>>(Wv, wTv, D_, D_);
  transpose_cvt_kernel<<<dim3(32, 32), dim3(256), 0, stream>>>(Wo, wTo, D_, D_);
  transpose_cvt_kernel<<<dim3(32, 128), dim3(256), 0, stream>>>(W1, w1T, D_, FF_);
  transpose_cvt_kernel<<<dim3(128, 32), dim3(256), 0, stream>>>(W2, w2T, FF_, D_);

  gemm_qkv<<<dim3(32, 24), dim3(256), 0, stream>>>(xb, wTq, bq, bk, bv, qb, kb, vb);

  attn_kernel<<<dim3(S_ / 64, B_ * H_), dim3(256), 0, stream>>>(qb, kb, vb, mask, ao);

  // proj: 128x128 split-K x2 (512 blocks, 2/CU), partials to proj[0],proj[1]
  gemm_bt_sk2<<<dim3(32, 8, 2), dim3(256), 0, stream>>>(ao, wTo, bo, proj, 4096, 1024, 1024, 512);

  ln_kernel<<<dim3(4096), dim3(256), 0, stream>>>(
      x, proj, proj + (size_t)4096 * 1024, g1, be1, x1f, x1b);

  gemm_bt_relu<<<dim3(32, 32), dim3(256), 0, stream>>>(x1b, w1T, b1, h1, 4096, 4096, 1024);

  // ffn2: split-K x2 over K=4096, partials to ffn2[0], ffn2[1]
  gemm_bt_sk2<<<dim3(32, 8, 2), dim3(256), 0, stream>>>(h1, w2T, b2, ffn2, 4096, 1024, 4096, 2048);

  ln_kernel<<<dim3(4096), dim3(256), 0, stream>>>(
      x1f, ffn2, ffn2 + (size_t)4096 * 1024, g2, be2, (float*)d_out, (u16*)nullptr);
}